// Round 1
// baseline (1037.058 us; speedup 1.0000x reference)
//
#include <hip/hip_runtime.h>
#include <hip/hip_bf16.h>

// DimeNet InteractionBlock, MI355X/gfx950.
// Float tensors are FLOAT32 at the memory interface; internal GEMMs bf16 MFMA.
// Stage A (kA): e_down = silu( (silu(x Wkj+b) * silu(rbf Wrbf2+b)) Wdown + b )  [E,128] bf16 -> ws
// Sort  (kHist/kScan1/kScan2/kScan3/kScatter): counting-sort triplet ids by idx_ji -> trip[]
// Stage B (kB): process triplets in sorted order; t = silu( (e_down[idx_kj] * s) Wup + b );
//               per-lane segmented reduction over sorted idx_ji runs, then f32 atomicAdd
//               directly into d_out (acts as mb). 2.3x fewer atomics + L2-local lines.
// Stage C (kC): out = mb + silu(silu(mb Wr1a+b) Wr1b+b) + x  (in place on d_out)
//
// R4 change: kB was atomic-bound (500MB WRITE_SIZE = every atomic line written back,
// 276G atomics/s, MfmaUtil 7%). Sort by idx_ji + in-register segment sums cut atomic
// count 128M->~56M and make scatter lines L2-resident. mb now aliases d_out (ws ~70MB).

#define HD 128

typedef short  short8 __attribute__((ext_vector_type(8)));
typedef __bf16 bf16x8 __attribute__((ext_vector_type(8)));
typedef float  f32x4  __attribute__((ext_vector_type(4)));

__device__ __forceinline__ float b2f(short s) {
    unsigned u = ((unsigned)(unsigned short)s) << 16;
    return __builtin_bit_cast(float, u);
}
__device__ __forceinline__ short f2b(float f) {
    return __builtin_bit_cast(short, __float2bfloat16(f));
}
__device__ __forceinline__ float silu_f(float v) {
    return v * __builtin_amdgcn_rcpf(1.0f + __expf(-v));
}
__device__ __forceinline__ short8 ld8(const short* p) { return *(const short8*)p; }

__device__ __forceinline__ f32x4 mfma16(short8 a, short8 b, f32x4 c) {
    return __builtin_amdgcn_mfma_f32_16x16x32_bf16(
        __builtin_bit_cast(bf16x8, a), __builtin_bit_cast(bf16x8, b), c, 0, 0, 0);
}

// Convert 8 consecutive f32 at p to a bf16 short8 fragment chunk.
__device__ __forceinline__ short8 ld8f(const float* p) {
    f32x4 v0 = *(const f32x4*)p;
    f32x4 v1 = *(const f32x4*)(p + 4);
    short8 r;
#pragma unroll
    for (int j = 0; j < 4; j++) { r[j] = f2b(v0[j]); r[4 + j] = f2b(v1[j]); }
    return r;
}

// Pack f32 weight W[K x 128] (row-major) into LDS bf16 fragment order:
// frag[((ct*KC+kc)*64 + lane)*8 + j] = B[k=kc*32+(lane>>4)*8+j][n=ct*16+(lane&15)]
__device__ void pack_weight(const float* __restrict__ W, int Kact, int KC,
                            short* frag, int tid, int nth) {
    int total = 8 * KC * 64;
    for (int e = tid; e < total; e += nth) {
        int lane = e & 63;
        int slot = e >> 6;          // ct*KC + kc
        int ct = slot / KC;
        int kc = slot - ct * KC;
        int n  = ct * 16 + (lane & 15);
        int kb = kc * 32 + (lane >> 4) * 8;
        short8 v;
#pragma unroll
        for (int j = 0; j < 8; j++) {
            int k = kb + j;
            v[j] = (k < Kact) ? f2b(W[k * HD + n]) : (short)0;
        }
        *(short8*)&frag[(slot * 64 + lane) * 8] = v;
    }
}

template <int KC>
__device__ __forceinline__ void gemm8(const short8* a, const short* fragW,
                                      int lane, f32x4* acc) {
#pragma unroll
    for (int kc = 0; kc < KC; kc++) {
#pragma unroll
        for (int ct = 0; ct < 8; ct++) {
            short8 b = ld8(&fragW[((ct * KC + kc) * 64 + lane) * 8]);
            acc[ct] = mfma16(a[kc], b, acc[ct]);
        }
    }
}

#define RT_S 136  // round-trip tile stride (bf16 elems); 272B rows, 16B-aligned

// ---------------- Stage A (14 waves) ----------------
extern "C" __global__ __launch_bounds__(896)
void kA(const float* __restrict__ x, const float* __restrict__ rbf,
        const float* __restrict__ Wkj, const float* __restrict__ bkj,
        const float* __restrict__ Wrbf2, const float* __restrict__ brbf2,
        const float* __restrict__ Wdown, const float* __restrict__ bdown,
        short* __restrict__ e_down, int ntiles) {
    extern __shared__ short smem[];
    short* fW1 = smem;               // 16384 shorts each
    short* fW2 = fW1 + 16384;
    short* fW3 = fW2 + 16384;
    short* rt0 = fW3 + 16384;        // 14 waves * 16*RT_S
    int tid = threadIdx.x;
    pack_weight(Wkj,   HD, 4, fW1, tid, 896);
    pack_weight(Wrbf2, HD, 4, fW2, tid, 896);
    pack_weight(Wdown, HD, 4, fW3, tid, 896);
    __syncthreads();
    int lane = tid & 63, wave = tid >> 6;
    int m = lane & 15, q = lane >> 4;
    short* rt = rt0 + wave * (16 * RT_S);

    for (int tile = blockIdx.x * 14 + wave; tile < ntiles; tile += gridDim.x * 14) {
        long rowbase = (long)tile * 16;
        const float* xr = x   + (rowbase + m) * HD;
        const float* rr = rbf + (rowbase + m) * HD;
        short8 ax[4], ar[4];
#pragma unroll
        for (int kc = 0; kc < 4; kc++) {
            ax[kc] = ld8f(xr + kc * 32 + q * 8);
            ar[kc] = ld8f(rr + kc * 32 + q * 8);
        }
        f32x4 acc1[8], acc2[8];
#pragma unroll
        for (int ct = 0; ct < 8; ct++) { acc1[ct] = (f32x4){0,0,0,0}; acc2[ct] = (f32x4){0,0,0,0}; }
#pragma unroll
        for (int kc = 0; kc < 4; kc++) {
#pragma unroll
            for (int ct = 0; ct < 8; ct++) {
                acc1[ct] = mfma16(ax[kc], ld8(&fW1[((ct*4+kc)*64 + lane)*8]), acc1[ct]);
                acc2[ct] = mfma16(ar[kc], ld8(&fW2[((ct*4+kc)*64 + lane)*8]), acc2[ct]);
            }
        }
        // h = silu(.)*silu(.)  -> LDS (C-layout write)
#pragma unroll
        for (int ct = 0; ct < 8; ct++) {
            int col = ct * 16 + m;
            float bk = bkj[col];
            float br = brbf2[col];
#pragma unroll
            for (int r = 0; r < 4; r++) {
                float h = silu_f(acc1[ct][r] + bk) * silu_f(acc2[ct][r] + br);
                rt[(q*4 + r) * RT_S + col] = f2b(h);
            }
        }
        short8 ah[4];
#pragma unroll
        for (int kc = 0; kc < 4; kc++) ah[kc] = ld8(&rt[m * RT_S + kc * 32 + q * 8]);
        f32x4 acc3[8];
#pragma unroll
        for (int ct = 0; ct < 8; ct++) acc3[ct] = (f32x4){0,0,0,0};
        gemm8<4>(ah, fW3, lane, acc3);
#pragma unroll
        for (int ct = 0; ct < 8; ct++) {
            int col = ct * 16 + m;
            float bd = bdown[col];
#pragma unroll
            for (int r = 0; r < 4; r++)
                rt[(q*4 + r) * RT_S + col] = f2b(silu_f(acc3[ct][r] + bd));
        }
        short* eg = e_down + (rowbase + m) * HD;
#pragma unroll
        for (int kc = 0; kc < 4; kc++)
            *(short8*)(eg + kc * 32 + q * 8) = ld8(&rt[m * RT_S + kc * 32 + q * 8]);
    }
}

// ---------------- sort kernels: counting sort of triplets by idx_ji ----------------
extern "C" __global__ __launch_bounds__(1024)
void kHist(const int* __restrict__ idx_ji, int* __restrict__ counts, int T) {
    for (int t = blockIdx.x * 1024 + threadIdx.x; t < T; t += gridDim.x * 1024)
        atomicAdd(&counts[idx_ji[t]], 1);
}

extern "C" __global__ __launch_bounds__(1024)
void kScan1(const int* __restrict__ counts, int* __restrict__ cursor,
            int* __restrict__ bsum, int E) {
    __shared__ int wpart[16];
    int i = blockIdx.x * 1024 + threadIdx.x;
    int lane = threadIdx.x & 63, wv = threadIdx.x >> 6;
    int orig = (i < E) ? counts[i] : 0;
    int v = orig;
#pragma unroll
    for (int d = 1; d < 64; d <<= 1) {
        int n = __shfl_up(v, d);
        if (lane >= d) v += n;
    }
    if (lane == 63) wpart[wv] = v;
    __syncthreads();
    if (wv == 0) {
        int w = (lane < 16) ? wpart[lane] : 0;
#pragma unroll
        for (int d = 1; d < 16; d <<= 1) {
            int n = __shfl_up(w, d);
            if (lane >= d) w += n;
        }
        if (lane < 16) wpart[lane] = w;
    }
    __syncthreads();
    int base = (wv > 0) ? wpart[wv - 1] : 0;
    if (i < E) cursor[i] = base + v - orig;        // block-local exclusive
    if (threadIdx.x == 1023) bsum[blockIdx.x] = base + v;  // block total
}

extern "C" __global__ void kScan2(int* __restrict__ bsum, int nb) {
    if (threadIdx.x == 0) {
        int run = 0;
        for (int b = 0; b < nb; b++) { int t = bsum[b]; bsum[b] = run; run += t; }
    }
}

extern "C" __global__ __launch_bounds__(1024)
void kScan3(int* __restrict__ cursor, const int* __restrict__ bsum, int E) {
    int i = blockIdx.x * 1024 + threadIdx.x;
    if (i < E) cursor[i] += bsum[blockIdx.x];      // global exclusive offsets
}

extern "C" __global__ __launch_bounds__(1024)
void kScatter(const int* __restrict__ idx_ji, int* __restrict__ cursor,
              int* __restrict__ trip, int T) {
    for (int t = blockIdx.x * 1024 + threadIdx.x; t < T; t += gridDim.x * 1024) {
        int p = atomicAdd(&cursor[idx_ji[t]], 1);
        trip[p] = t;
    }
}

// ---------------- Stage B (16 waves, sorted triplets, st aliased into rt) ----------------
extern "C" __global__ __launch_bounds__(1024)
void kB(const float* __restrict__ sbf, const int* __restrict__ idx_kj,
        const int* __restrict__ idx_ji, const int* __restrict__ trip,
        const float* __restrict__ W1, const float* __restrict__ W2,
        const float* __restrict__ Wup, const float* __restrict__ bup,
        const short* __restrict__ e_down, float* __restrict__ mb, int ntiles) {
    extern __shared__ short smem[];
    short* f1  = smem;               // 8192 shorts
    short* f2  = f1 + 8192;          // 16384
    short* f3  = f2 + 16384;         // 16384
    short* rt0 = f3 + 16384;         // 16 waves * 16*RT_S (st aliases rt)
    int tid = threadIdx.x;
    pack_weight(W1, 42, 2, f1, tid, 1024);
    pack_weight(W2, HD, 4, f2, tid, 1024);
    pack_weight(Wup, HD, 4, f3, tid, 1024);
    __syncthreads();
    int lane = tid & 63, wave = tid >> 6;
    int m = lane & 15, q = lane >> 4;
    short* rt = rt0 + wave * (16 * RT_S);
    short* st = rt;                  // alias: st [16][72] lives in rt's space
    int* sti = (int*)st;
    const float2* sg2 = (const float2*)sbf;   // 21 float2 per 42-f32 row

    for (int tile = blockIdx.x * 16 + wave; tile < ntiles; tile += gridDim.x * 16) {
        long rowbase = (long)tile * 16;
        // sorted triplet ids + edge ids for this tile's 16 rows (held in lanes 0..15)
        int tr_l = trip[rowbase + m];
        int ji_l = idx_ji[tr_l];
        // zero [16][72] bf16 tile (2304B), fill cols 0..41 via gathered float2 loads
#pragma unroll
        for (int i = 0; i < 9; i++) sti[lane + i * 64] = 0;
#pragma unroll
        for (int i = lane; i < 336; i += 64) {
            int r = i / 21, d = i - r * 21;
            int trr = __shfl(tr_l, r);           // triplet id of row r
            float2 v = sg2[(long)trr * 21 + d];
            st[r * 72 + d * 2]     = f2b(v.x);
            st[r * 72 + d * 2 + 1] = f2b(v.y);
        }
        // GEMM1: [16,64pad] x W1
        short8 a0[2];
        a0[0] = ld8(&st[m * 72 + q * 8]);
        a0[1] = ld8(&st[m * 72 + 32 + q * 8]);
        f32x4 acc[8];
#pragma unroll
        for (int ct = 0; ct < 8; ct++) acc[ct] = (f32x4){0,0,0,0};
        gemm8<2>(a0, f1, lane, acc);
#pragma unroll
        for (int ct = 0; ct < 8; ct++) {
            int col = ct * 16 + m;
#pragma unroll
            for (int r = 0; r < 4; r++)
                rt[(q*4 + r) * RT_S + col] = f2b(silu_f(acc[ct][r]));
        }
        // GEMM2
        short8 a1[4];
#pragma unroll
        for (int kc = 0; kc < 4; kc++) a1[kc] = ld8(&rt[m * RT_S + kc * 32 + q * 8]);
#pragma unroll
        for (int ct = 0; ct < 8; ct++) acc[ct] = (f32x4){0,0,0,0};
        gemm8<4>(a1, f2, lane, acc);
#pragma unroll
        for (int ct = 0; ct < 8; ct++) {
            int col = ct * 16 + m;
#pragma unroll
            for (int r = 0; r < 4; r++)
                rt[(q*4 + r) * RT_S + col] = f2b(silu_f(acc[ct][r]));
        }
        // gather e_down[idx_kj[trip]] (A-layout), multiply by s, GEMM3 with Wup
        int ikj = idx_kj[tr_l];
        const short* ep = e_down + (long)ikj * HD;
        short8 p[4];
#pragma unroll
        for (int kc = 0; kc < 4; kc++) {
            short8 ek = ld8(ep + kc * 32 + q * 8);
            short8 ss = ld8(&rt[m * RT_S + kc * 32 + q * 8]);
            short8 pr;
#pragma unroll
            for (int j = 0; j < 8; j++) pr[j] = f2b(b2f(ss[j]) * b2f(ek[j]));
            p[kc] = pr;
        }
        f32x4 acc3[8];
#pragma unroll
        for (int ct = 0; ct < 8; ct++) acc3[ct] = (f32x4){0,0,0,0};
        gemm8<4>(p, f3, lane, acc3);
        // t = silu(. + bup); segmented in-register reduction over sorted idx_ji runs,
        // then one f32 atomicAdd per (run, col). Rows of this lane's quad: q*4 + r.
        int jb[4];
#pragma unroll
        for (int r = 0; r < 4; r++) jb[r] = __shfl(ji_l, q * 4 + r);
#pragma unroll
        for (int ct = 0; ct < 8; ct++) {
            int col = ct * 16 + m;
            float bu = bup[col];
            float run = 0.f;
#pragma unroll
            for (int r = 0; r < 4; r++) {
                run += silu_f(acc3[ct][r] + bu);
                if (r == 3 || jb[r] != jb[r + 1]) {
                    unsafeAtomicAdd(&mb[(long)jb[r] * HD + col], run);
                    run = 0.f;
                }
            }
        }
    }
}

// ---------------- Stage C (16 waves; mb/out alias d_out, in-place) ----------------
extern "C" __global__ __launch_bounds__(1024)
void kC(const float* mb, const float* __restrict__ x,
        const float* __restrict__ Wa, const float* __restrict__ ba,
        const float* __restrict__ Wb, const float* __restrict__ bb2,
        float* out, int ntiles) {
    extern __shared__ short smem[];
    short* f1  = smem;
    short* f2  = f1 + 16384;
    short* rt0 = f2 + 16384;
    int tid = threadIdx.x;
    pack_weight(Wa, HD, 4, f1, tid, 1024);
    pack_weight(Wb, HD, 4, f2, tid, 1024);
    __syncthreads();
    int lane = tid & 63, wave = tid >> 6;
    int m = lane & 15, q = lane >> 4;
    short* rt = rt0 + wave * (16 * RT_S);

    for (int tile = blockIdx.x * 16 + wave; tile < ntiles; tile += gridDim.x * 16) {
        long rowbase = (long)tile * 16;
        const float* mr = mb + (rowbase + m) * HD;
        short8 am[4];
#pragma unroll
        for (int kc = 0; kc < 4; kc++) am[kc] = ld8f(mr + kc * 32 + q * 8);
        f32x4 acc[8];
#pragma unroll
        for (int ct = 0; ct < 8; ct++) acc[ct] = (f32x4){0,0,0,0};
        gemm8<4>(am, f1, lane, acc);
#pragma unroll
        for (int ct = 0; ct < 8; ct++) {
            int col = ct * 16 + m;
            float bav = ba[col];
#pragma unroll
            for (int r = 0; r < 4; r++)
                rt[(q*4 + r) * RT_S + col] = f2b(silu_f(acc[ct][r] + bav));
        }
        short8 ah[4];
#pragma unroll
        for (int kc = 0; kc < 4; kc++) ah[kc] = ld8(&rt[m * RT_S + kc * 32 + q * 8]);
#pragma unroll
        for (int ct = 0; ct < 8; ct++) acc[ct] = (f32x4){0,0,0,0};
        gemm8<4>(ah, f2, lane, acc);
        // out = mb + silu(. + bb) + x  (in place: each element read+written by same lane)
#pragma unroll
        for (int ct = 0; ct < 8; ct++) {
            int col = ct * 16 + m;
            float bbv = bb2[col];
#pragma unroll
            for (int r = 0; r < 4; r++) {
                long grow = rowbase + q * 4 + r;
                float mv = mb[grow * HD + col];
                out[grow * HD + col] = mv + silu_f(acc[ct][r] + bbv)
                                     + x[grow * HD + col];
            }
        }
    }
}

extern "C" void kernel_launch(void* const* d_in, const int* in_sizes, int n_in,
                              void* d_out, int out_size, void* d_ws, size_t ws_size,
                              hipStream_t stream) {
    const float* x      = (const float*)d_in[0];
    const float* rbf    = (const float*)d_in[1];
    const float* sbf    = (const float*)d_in[2];
    const int*   idx_kj = (const int*)d_in[3];
    const int*   idx_ji = (const int*)d_in[4];
    const float* W_rbf2 = (const float*)d_in[5];
    const float* b_rbf2 = (const float*)d_in[6];
    const float* W_sbf1 = (const float*)d_in[7];
    const float* W_sbf2 = (const float*)d_in[8];
    const float* W_kj   = (const float*)d_in[9];
    const float* b_kj   = (const float*)d_in[10];
    const float* W_down = (const float*)d_in[11];
    const float* b_down = (const float*)d_in[12];
    const float* W_up   = (const float*)d_in[13];
    const float* b_up   = (const float*)d_in[14];
    const float* W_r1a  = (const float*)d_in[15];
    const float* b_r1a  = (const float*)d_in[16];
    const float* W_r1b  = (const float*)d_in[17];
    const float* b_r1b  = (const float*)d_in[18];

    int E = in_sizes[0] / HD;
    int T = in_sizes[3];

    // ws layout (~70 MB): e_down | trip | cursor | counts | bsum
    short* e_down = (short*)d_ws;                                   // E*128 bf16
    char*  wp = (char*)d_ws + (size_t)E * HD * 2;
    int* trip   = (int*)wp;  wp += (size_t)T * 4;
    int* cursor = (int*)wp;  wp += (size_t)E * 4;
    int* counts = (int*)wp;  wp += (size_t)E * 4;
    int* bsum   = (int*)wp;

    float* mb = (float*)d_out;   // accumulate scatter directly into d_out

    hipMemsetAsync(counts, 0, (size_t)E * 4, stream);
    hipMemsetAsync(mb, 0, (size_t)E * HD * 4, stream);

    int ntA = E / 16;
    int ntB = T / 16;
    int nblkE = (E + 1023) / 1024;
    size_t ldsA = (size_t)(3 * 16384 + 14 * 16 * RT_S) * 2;    // 159232 B
    size_t ldsB = (size_t)(8192 + 16384 + 16384 + 16 * 16 * RT_S) * 2;  // 151552 B
    size_t ldsC = (size_t)(2 * 16384 + 16 * 16 * RT_S) * 2;    // 135168 B

    // counting sort of triplets by idx_ji
    kHist   <<<512, 1024, 0, stream>>>(idx_ji, counts, T);
    kScan1  <<<nblkE, 1024, 0, stream>>>(counts, cursor, bsum, E);
    kScan2  <<<1, 64, 0, stream>>>(bsum, nblkE);
    kScan3  <<<nblkE, 1024, 0, stream>>>(cursor, bsum, E);
    kScatter<<<512, 1024, 0, stream>>>(idx_ji, cursor, trip, T);

    kA<<<256, 896, ldsA, stream>>>(x, rbf, W_kj, b_kj, W_rbf2, b_rbf2,
                                   W_down, b_down, e_down, ntA);
    kB<<<256, 1024, ldsB, stream>>>(sbf, idx_kj, idx_ji, trip, W_sbf1, W_sbf2,
                                    W_up, b_up, e_down, mb, ntB);
    kC<<<256, 1024, ldsC, stream>>>(mb, x, W_r1a, b_r1a, W_r1b, b_r1b,
                                    (float*)d_out, ntA);
}